// Round 1
// 408.772 us; speedup vs baseline: 1.0150x; 1.0150x over previous
//
#include <hip/hip_runtime.h>

// FoldLayer (col2im overlap-add), uniform 2x2-block gather formulation.
//
// v5: instead of one thread per output pixel with a parity-dependent 1..4
// predicated gather (divergent within every wave: adjacent half-waves have
// opposite wp parity), one thread owns a 2x2 output pixel block. The 9
// contributions of a 2x2 block map exactly onto the 9 kernel slices of 4
// patches:
//   patch (t,u):     slices (1,1)=4 (1,2)=5 (2,1)=7 (2,2)=8   always valid
//   patch (t,u+1):   slices (1,0)=3 (2,0)=6                   valid if u<63
//   patch (t+1,u):   slices (0,1)=1 (0,2)=2                   valid if t<63
//   patch (t+1,u+1): slice  (0,0)=0                           valid if both
// Pixel accumulation:
//   out(2t  ,2u  ) = s4
//   out(2t  ,2u+1) = s5 + s3'
//   out(2t+1,2u  ) = s7 + s1''
//   out(2t+1,2u+1) = s8 + s6' + s2'' + s0'''
// Branch-free in the interior; every patch slice read exactly once (border
// slices that fold into the cropped pad are never touched). 18 nontemporal
// 16B loads + 8 stores in flight per thread (2 batches: b and b+8).
//
// Shapes: patches (B=16, GH=64, GW=64, 9*128) fp32 kernel-major;
// out (16, 128, 128, 128) fp32.

#define GH 64
#define GW 64

typedef float v4f __attribute__((ext_vector_type(4)));

__global__ __launch_bounds__(256) void fold_block_kernel(
    const v4f* __restrict__ p, v4f* __restrict__ out) {
    const int PSTRIDE     = 288;                 // 3*3*128/4 float4 per patch
    const int ROWSTRIDE   = GW * PSTRIDE;        // float4 per patch row
    const int BSTRIDE_IN  = GH * GW * PSTRIDE;   // per-batch input float4
    const int BSTRIDE_OUT = 128 * 128 * 32;      // per-batch output float4

    int tid = blockIdx.x * 256 + threadIdx.x;
    int c4 = tid & 31;           // float4 channel group, 32 per pixel
    int bx = (tid >> 5) & 63;    // output 2x2-block col == patch col u
    int by = (tid >> 11) & 63;   // output 2x2-block row == patch row t
    int b  = tid >> 17;          // [0,8); partner batch is b+8

    bool tOk = (by < GH - 1);
    bool uOk = (bx < GW - 1);

    const v4f* q0 = p + ((b * GH + by) * GW + bx) * PSTRIDE + c4;  // patch (t,u), batch b
    const v4f* q1 = q0 + 8 * BSTRIDE_IN;                           // batch b+8

    // patch (t,u): slices 4,5,7,8 — unconditional
    v4f a00 = __builtin_nontemporal_load(q0 + 4 * 32);
    v4f c00 = __builtin_nontemporal_load(q1 + 4 * 32);
    v4f a01 = __builtin_nontemporal_load(q0 + 5 * 32);
    v4f c01 = __builtin_nontemporal_load(q1 + 5 * 32);
    v4f a10 = __builtin_nontemporal_load(q0 + 7 * 32);
    v4f c10 = __builtin_nontemporal_load(q1 + 7 * 32);
    v4f a11 = __builtin_nontemporal_load(q0 + 8 * 32);
    v4f c11 = __builtin_nontemporal_load(q1 + 8 * 32);

    if (uOk) {  // patch (t,u+1): slice 3 -> pix(2t,2u+1), slice 6 -> pix(2t+1,2u+1)
        const v4f* r0 = q0 + PSTRIDE;
        const v4f* r1 = q1 + PSTRIDE;
        a01 += __builtin_nontemporal_load(r0 + 3 * 32);
        c01 += __builtin_nontemporal_load(r1 + 3 * 32);
        a11 += __builtin_nontemporal_load(r0 + 6 * 32);
        c11 += __builtin_nontemporal_load(r1 + 6 * 32);
    }
    if (tOk) {  // patch (t+1,u): slice 1 -> pix(2t+1,2u), slice 2 -> pix(2t+1,2u+1)
        const v4f* r0 = q0 + ROWSTRIDE;
        const v4f* r1 = q1 + ROWSTRIDE;
        a10 += __builtin_nontemporal_load(r0 + 1 * 32);
        c10 += __builtin_nontemporal_load(r1 + 1 * 32);
        a11 += __builtin_nontemporal_load(r0 + 2 * 32);
        c11 += __builtin_nontemporal_load(r1 + 2 * 32);
        if (uOk) {  // patch (t+1,u+1): slice 0 -> pix(2t+1,2u+1)
            a11 += __builtin_nontemporal_load(r0 + ROWSTRIDE - ROWSTRIDE + PSTRIDE + 0 * 32);
            c11 += __builtin_nontemporal_load(r1 + PSTRIDE + 0 * 32);
        }
    }

    // stores: pixels (2t,2u),(2t,2u+1),(2t+1,2u),(2t+1,2u+1), batches b and b+8
    int o = ((b * 128 + 2 * by) * 128 + 2 * bx) * 32 + c4;
    v4f* w0 = out + o;
    v4f* w1 = w0 + 8 * BSTRIDE_OUT;
    __builtin_nontemporal_store(a00, w0);
    __builtin_nontemporal_store(a01, w0 + 32);
    __builtin_nontemporal_store(a10, w0 + 128 * 32);
    __builtin_nontemporal_store(a11, w0 + 128 * 32 + 32);
    __builtin_nontemporal_store(c00, w1);
    __builtin_nontemporal_store(c01, w1 + 32);
    __builtin_nontemporal_store(c10, w1 + 128 * 32);
    __builtin_nontemporal_store(c11, w1 + 128 * 32 + 32);
}

extern "C" void kernel_launch(void* const* d_in, const int* in_sizes, int n_in,
                              void* d_out, int out_size, void* d_ws, size_t ws_size,
                              hipStream_t stream) {
    const v4f* p = (const v4f*)d_in[0];
    v4f* out = (v4f*)d_out;
    // 8 batch-pairs x 64 x 64 blocks x 32 channel-groups = 1,048,576 threads
    dim3 block(256);
    dim3 grid(1048576 / 256);  // 4096 blocks
    fold_block_kernel<<<grid, block, 0, stream>>>(p, out);
}